// Round 3
// baseline (217.847 us; speedup 1.0000x reference)
//
#include <hip/hip_runtime.h>

// AtlasAttention bf16-MFMA, fused-MLP version.
// out = MLP2(relu(MLP1(poly(clip(X@Wq)))))[:, :64], heads folded.
// q flat layout == out flat layout == [row*64+d] (row = token*12+head), so q (fp32)
// is staged in d_out; the fused MLP kernel reads q rows and overwrites the SAME rows
// (block-local, no cross-block hazard). H never touches HBM (lives in LDS per block).
//
// ws layout (bytes):
//   Xb   @ 0          : 8192*768 bf16   = 12,582,912
//   Wqb  @ 12,582,912 : 768*768  bf16^T = 1,179,648   (Wqb[n][k])
//   W1b  @ 13,762,560 : 512*256  bf16^T = 262,144     (W1b[n][k])
//   W2b  @ 14,024,704 : 64*512   bf16^T = 65,536      (W2b[n][k], first 64 cols of W2)

typedef unsigned short u16;
typedef __attribute__((ext_vector_type(8))) short short8;
typedef __attribute__((ext_vector_type(4))) float f32x4;
typedef __attribute__((ext_vector_type(4))) u16 u16x4;

__device__ __forceinline__ u16 f2bf(float f) {
    unsigned u = __builtin_bit_cast(unsigned, f);
    u += 0x7FFFu + ((u >> 16) & 1u);   // RNE
    return (u16)(u >> 16);
}

__device__ __forceinline__ void gl2lds16(const void* g, void* l) {
    __builtin_amdgcn_global_load_lds(
        (const __attribute__((address_space(1))) unsigned int*)g,
        (__attribute__((address_space(3))) unsigned int*)l, 16, 0, 0);
}

// ---------------- conversion kernels ----------------

__global__ __launch_bounds__(256) void cast_f32_bf16(const float* __restrict__ in,
                                                     u16* __restrict__ out, int n4) {
    int i = blockIdx.x * 256 + threadIdx.x;
    if (i < n4) {
        float4 v = reinterpret_cast<const float4*>(in)[i];
        u16x4 o = {f2bf(v.x), f2bf(v.y), f2bf(v.z), f2bf(v.w)};
        reinterpret_cast<u16x4*>(out)[i] = o;
    }
}

// in: [R][Cin] fp32; out: [C][R] bf16 (first C cols). grid (C/32, R/32), block (32,8).
__global__ __launch_bounds__(256) void transpose_cast(const float* __restrict__ in,
                                                      u16* __restrict__ out,
                                                      int R, int Cin) {
    __shared__ float t[32][33];
    const int c0 = blockIdx.x * 32, r0 = blockIdx.y * 32;
    const int tx = threadIdx.x, ty = threadIdx.y;
    #pragma unroll
    for (int j = 0; j < 32; j += 8)
        t[ty + j][tx] = in[(size_t)(r0 + ty + j) * Cin + c0 + tx];
    __syncthreads();
    #pragma unroll
    for (int j = 0; j < 32; j += 8)
        out[(size_t)(c0 + ty + j) * R + r0 + tx] = f2bf(t[tx][ty + j]);
}

// ---------------- GEMM1: q = Xb @ Wqb^T (m97-style MFMA GEMM) ----------------

template<int BM, int BN, int WTM, int WTN, int K, int LDA, int LDB, int LDC>
__global__ __launch_bounds__(256)
void mfma_gemm(const u16* __restrict__ A, const u16* __restrict__ B,
               float* __restrict__ C)
{
    constexpr int MT = WTM / 16, NT = WTN / 16, GM = BM / WTM;
    __shared__ u16 As[BM * 32];
    __shared__ u16 Bs[BN * 32];

    const int tid = threadIdx.x;
    const int w = tid >> 6, lane = tid & 63;
    const int lrow = lane >> 2, lslot = lane & 3;
    const int m16 = lane & 15, quad = lane >> 4;
    const int bm = blockIdx.x * BM, bn = blockIdx.y * BN;
    const int wr = (w % GM) * WTM, wc = (w / GM) * WTN;

    f32x4 acc[MT][NT];
    #pragma unroll
    for (int i = 0; i < MT; ++i)
        #pragma unroll
        for (int j = 0; j < NT; ++j)
            acc[i][j] = (f32x4){0.f, 0.f, 0.f, 0.f};

    for (int k0 = 0; k0 < K; k0 += 32) {
        #pragma unroll
        for (int i = 0; i < BN / 64; ++i) {
            const int row = (w * (BN / 64) + i) * 16 + lrow;
            const int c = lslot ^ ((row >> 2) & 3);
            gl2lds16(B + (size_t)(bn + row) * LDB + k0 + c * 8,
                     &Bs[row * 32 + lslot * 8]);
        }
        #pragma unroll
        for (int i = 0; i < BM / 64; ++i) {
            const int row = (w * (BM / 64) + i) * 16 + lrow;
            const int c = lslot ^ ((row >> 2) & 3);
            gl2lds16(A + (size_t)(bm + row) * LDA + k0 + c * 8,
                     &As[row * 32 + lslot * 8]);
        }
        __syncthreads();

        short8 af[MT], bf[NT];
        #pragma unroll
        for (int i = 0; i < MT; ++i) {
            const int row = wr + i * 16 + m16;
            const int s = quad ^ ((row >> 2) & 3);
            af[i] = *reinterpret_cast<const short8*>(&As[row * 32 + s * 8]);
        }
        #pragma unroll
        for (int j = 0; j < NT; ++j) {
            const int row = wc + j * 16 + m16;
            const int s = quad ^ ((row >> 2) & 3);
            bf[j] = *reinterpret_cast<const short8*>(&Bs[row * 32 + s * 8]);
        }
        #pragma unroll
        for (int i = 0; i < MT; ++i)
            #pragma unroll
            for (int j = 0; j < NT; ++j)
                acc[i][j] = __builtin_amdgcn_mfma_f32_16x16x32_bf16(
                    af[i], bf[j], acc[i][j], 0, 0, 0);
        __syncthreads();
    }

    #pragma unroll
    for (int j = 0; j < NT; ++j) {
        const int col = bn + wc + j * 16 + m16;
        #pragma unroll
        for (int i = 0; i < MT; ++i)
            #pragma unroll
            for (int r = 0; r < 4; ++r) {
                const int row = bm + wr + i * 16 + quad * 4 + r;
                C[(size_t)row * LDC + col] = acc[i][j][r];
            }
    }
}

// ---------------- fused MLP: out = relu(poly(q)@W1^T+b1) @ W2c^T + b2 ----------------
// One block = 64 rows. LDS: As = poly(q) [64][256] bf16 (full K, staged once),
// Hs = H half [64][256] bf16. Swizzle: element k of row r lives at
// r*256 + slot*8 + (k&7), slot = (k>>3) ^ (r&7)  -> ds_read_b128 fragments are
// 2-way aliased = conflict-free. W1^T/W2^T B-fragments read directly from global
// (L2-resident; no LDS staging, no staging syncs in the stage-1 k-loop).

__global__ __launch_bounds__(256, 2)
void fused_mlp(const float* __restrict__ q,      // [ROWS][64] fp32 (aliases out)
               const u16* __restrict__ W1t,      // [512][256] bf16
               const float* __restrict__ b1,     // [512]
               const u16* __restrict__ W2t,      // [64][512] bf16
               const float* __restrict__ b2,     // [256] (first 64 used)
               const float* __restrict__ coeffs, // [4]
               float* __restrict__ out)          // [ROWS][64] fp32
{
    __shared__ u16 As[64 * 256];
    __shared__ u16 Hs[64 * 256];

    const int tid = threadIdx.x;
    const int w = tid >> 6, lane = tid & 63;
    const int m16 = lane & 15, quad = lane >> 4;
    const long bm = (long)blockIdx.x * 64;

    const float c0 = coeffs[0], c1 = coeffs[1], c2 = coeffs[2], c3 = coeffs[3];

    // ---- phase 0: poly-expand q -> As (64 rows x 256 k, swizzled bf16) ----
    {
        const int r = tid >> 2;      // row 0..63
        const int ci = tid & 3;
        const float* qrow = q + (bm + r) * 64;
        #pragma unroll
        for (int s = 0; s < 8; ++s) {
            const int c = ci + 4 * s;          // logical chunk, k = c*8
            const int k0 = c * 8;
            const int oct = k0 >> 6;
            const int d0 = k0 & 63;
            const float4 v0 = *reinterpret_cast<const float4*>(qrow + d0);
            const float4 v1 = *reinterpret_cast<const float4*>(qrow + d0 + 4);
            const float xs[8] = {v0.x, v0.y, v0.z, v0.w, v1.x, v1.y, v1.z, v1.w};
            const float coef = (oct == 0) ? c0 : (oct == 1) ? c1 : (oct == 2) ? c2 : c3;
            short8 sv;
            #pragma unroll
            for (int j = 0; j < 8; ++j) {
                float p;
                if (oct == 0) {
                    p = c0;
                } else {
                    const float x = fminf(fmaxf(xs[j], -10.f), 10.f);
                    float t = x;
                    if (oct >= 2) t *= x;
                    if (oct == 3) t *= x;
                    p = fminf(fmaxf(coef * t, -1e6f), 1e6f);
                }
                sv[j] = (short)f2bf(p);
            }
            const int slot = c ^ (r & 7);
            *reinterpret_cast<short8*>(&As[r * 256 + slot * 8]) = sv;
        }
    }
    __syncthreads();

    f32x4 acc2[4];
    #pragma unroll
    for (int j = 0; j < 4; ++j) acc2[j] = (f32x4){0.f, 0.f, 0.f, 0.f};

    #pragma unroll 1
    for (int h = 0; h < 2; ++h) {
        // ---- stage 1: H[:, h*256 : h*256+256], wave w owns cols w*64..w*64+64 ----
        f32x4 acc1[4][4];
        #pragma unroll
        for (int i = 0; i < 4; ++i)
            #pragma unroll
            for (int j = 0; j < 4; ++j)
                acc1[i][j] = (f32x4){0.f, 0.f, 0.f, 0.f};

        #pragma unroll 1
        for (int ks = 0; ks < 8; ++ks) {
            const int k0 = ks * 32;
            short8 af[4], bf[4];
            #pragma unroll
            for (int i = 0; i < 4; ++i) {
                const int row = i * 16 + m16;
                const int slot = ((k0 >> 3) + quad) ^ (row & 7);
                af[i] = *reinterpret_cast<const short8*>(&As[row * 256 + slot * 8]);
            }
            #pragma unroll
            for (int j = 0; j < 4; ++j) {
                const int n = h * 256 + w * 64 + j * 16 + m16;
                bf[j] = *reinterpret_cast<const short8*>(
                    &W1t[(size_t)n * 256 + k0 + quad * 8]);
            }
            #pragma unroll
            for (int i = 0; i < 4; ++i)
                #pragma unroll
                for (int j = 0; j < 4; ++j)
                    acc1[i][j] = __builtin_amdgcn_mfma_f32_16x16x32_bf16(
                        af[i], bf[j], acc1[i][j], 0, 0, 0);
        }

        // ---- store H half to Hs (bias + relu, bf16, swizzled) ----
        #pragma unroll
        for (int j = 0; j < 4; ++j) {
            const int nl = w * 64 + j * 16 + m16;      // local col 0..255
            const float bv = b1[h * 256 + nl];
            #pragma unroll
            for (int i = 0; i < 4; ++i) {
                #pragma unroll
                for (int r = 0; r < 4; ++r) {
                    const int row = i * 16 + quad * 4 + r;
                    const int slot = (nl >> 3) ^ (row & 7);
                    const float v = fmaxf(acc1[i][j][r] + bv, 0.f);
                    Hs[row * 256 + slot * 8 + (nl & 7)] = f2bf(v);
                }
            }
        }
        __syncthreads();

        // ---- stage 2 partial: out[64][64] += H_half @ W2c^T[:, this k half] ----
        // wave w owns rows w*16..w*16+16, all 64 cols, K=256 (this half).
        #pragma unroll 1
        for (int ks = 0; ks < 8; ++ks) {
            const int k0 = ks * 32;
            short8 hf;
            {
                const int row = w * 16 + m16;
                const int slot = ((k0 >> 3) + quad) ^ (row & 7);
                hf = *reinterpret_cast<const short8*>(&Hs[row * 256 + slot * 8]);
            }
            #pragma unroll
            for (int j = 0; j < 4; ++j) {
                const int n = j * 16 + m16;
                const short8 bf = *reinterpret_cast<const short8*>(
                    &W2t[(size_t)n * 512 + h * 256 + k0 + quad * 8]);
                acc2[j] = __builtin_amdgcn_mfma_f32_16x16x32_bf16(
                    hf, bf, acc2[j], 0, 0, 0);
            }
        }
        __syncthreads();   // Hs consumed; safe to overwrite next half
    }

    // ---- epilogue: out rows bm + w*16 + quad*4 + r ----
    #pragma unroll
    for (int j = 0; j < 4; ++j) {
        const int col = j * 16 + m16;
        const float bv = b2[col];
        #pragma unroll
        for (int r = 0; r < 4; ++r) {
            const long row = bm + w * 16 + quad * 4 + r;
            out[row * 64 + col] = acc2[j][r] + bv;
        }
    }
}

// ---------------- host ----------------

extern "C" void kernel_launch(void* const* d_in, const int* in_sizes, int n_in,
                              void* d_out, int out_size, void* d_ws, size_t ws_size,
                              hipStream_t stream) {
    const float* X      = (const float*)d_in[0];
    const float* Wq     = (const float*)d_in[1];
    const float* coeffs = (const float*)d_in[2];
    const float* W1     = (const float*)d_in[3];
    const float* b1     = (const float*)d_in[4];
    const float* W2     = (const float*)d_in[5];
    const float* b2     = (const float*)d_in[6];
    float* out = (float*)d_out;            // q staging (fp32) then final out

    char* ws = (char*)d_ws;
    u16* Xb  = (u16*)(ws);
    u16* Wqb = (u16*)(ws + 12582912);
    u16* W1b = (u16*)(ws + 13762560);
    u16* W2b = (u16*)(ws + 14024704);

    cast_f32_bf16<<<6144, 256, 0, stream>>>(X, Xb, 8192 * 768 / 4);
    transpose_cast<<<dim3(24, 24), dim3(32, 8), 0, stream>>>(Wq, Wqb, 768, 768);
    transpose_cast<<<dim3(16, 8),  dim3(32, 8), 0, stream>>>(W1, W1b, 256, 512);
    transpose_cast<<<dim3(2, 16),  dim3(32, 8), 0, stream>>>(W2, W2b, 512, 256);

    // GEMM1: q = Xb @ Wqb^T -> fp32 in d_out. M=8192 N=768 K=768.
    mfma_gemm<128, 128, 64, 64, 768, 768, 768, 768>
        <<<dim3(64, 6), 256, 0, stream>>>(Xb, Wqb, out);

    // Fused MLP over all 98304 rows; 64 rows/block.
    fused_mlp<<<1536, 256, 0, stream>>>(out, W1b, b1, W2b, b2, coeffs, out);
}

// Round 4
// 211.529 us; speedup vs baseline: 1.0299x; 1.0299x over previous
//
#include <hip/hip_runtime.h>

// AtlasAttention bf16-MFMA, fused-MLP v2 (latency-pipelined).
// out = MLP2(relu(MLP1(poly(clip(X@Wq)))))[:, :64], heads folded.
// q flat layout == out flat layout == [row*64+d] (row = token*12+head): q (fp32)
// is staged in d_out; fused kernel reads q rows and overwrites the same rows.
// H never touches HBM (per-block LDS).
//
// ws layout (bytes):
//   Xb   @ 0          : 8192*768 bf16   = 12,582,912
//   Wqb  @ 12,582,912 : 768*768  bf16^T = 1,179,648   (Wqb[n][k])
//   W1b  @ 13,762,560 : 512*256  bf16^T = 262,144     (W1b[n][k])
//   W2b  @ 14,024,704 : 64*512   bf16^T = 65,536      (W2b[n][k], first 64 cols of W2)

typedef unsigned short u16;
typedef __attribute__((ext_vector_type(8))) short short8;
typedef __attribute__((ext_vector_type(4))) float f32x4;
typedef __attribute__((ext_vector_type(4))) u16 u16x4;

__device__ __forceinline__ u16 f2bf(float f) {
    unsigned u = __builtin_bit_cast(unsigned, f);
    u += 0x7FFFu + ((u >> 16) & 1u);   // RNE
    return (u16)(u >> 16);
}

__device__ __forceinline__ void gl2lds16(const void* g, void* l) {
    __builtin_amdgcn_global_load_lds(
        (const __attribute__((address_space(1))) unsigned int*)g,
        (__attribute__((address_space(3))) unsigned int*)l, 16, 0, 0);
}

// ---------------- conversion kernels ----------------

__global__ __launch_bounds__(256) void cast_f32_bf16(const float* __restrict__ in,
                                                     u16* __restrict__ out, int n4) {
    int i = blockIdx.x * 256 + threadIdx.x;
    if (i < n4) {
        float4 v = reinterpret_cast<const float4*>(in)[i];
        u16x4 o = {f2bf(v.x), f2bf(v.y), f2bf(v.z), f2bf(v.w)};
        reinterpret_cast<u16x4*>(out)[i] = o;
    }
}

// in: [R][Cin] fp32; out: [C][R] bf16 (first C cols). grid (C/32, R/32), block (32,8).
__global__ __launch_bounds__(256) void transpose_cast(const float* __restrict__ in,
                                                      u16* __restrict__ out,
                                                      int R, int Cin) {
    __shared__ float t[32][33];
    const int c0 = blockIdx.x * 32, r0 = blockIdx.y * 32;
    const int tx = threadIdx.x, ty = threadIdx.y;
    #pragma unroll
    for (int j = 0; j < 32; j += 8)
        t[ty + j][tx] = in[(size_t)(r0 + ty + j) * Cin + c0 + tx];
    __syncthreads();
    #pragma unroll
    for (int j = 0; j < 32; j += 8)
        out[(size_t)(c0 + ty + j) * R + r0 + tx] = f2bf(t[tx][ty + j]);
}

// ---------------- GEMM1: q = Xb @ Wqb^T (m97-style MFMA GEMM) ----------------

template<int BM, int BN, int WTM, int WTN, int K, int LDA, int LDB, int LDC>
__global__ __launch_bounds__(256)
void mfma_gemm(const u16* __restrict__ A, const u16* __restrict__ B,
               float* __restrict__ C)
{
    constexpr int MT = WTM / 16, NT = WTN / 16, GM = BM / WTM;
    __shared__ u16 As[BM * 32];
    __shared__ u16 Bs[BN * 32];

    const int tid = threadIdx.x;
    const int w = tid >> 6, lane = tid & 63;
    const int lrow = lane >> 2, lslot = lane & 3;
    const int m16 = lane & 15, quad = lane >> 4;
    const int bm = blockIdx.x * BM, bn = blockIdx.y * BN;
    const int wr = (w % GM) * WTM, wc = (w / GM) * WTN;

    f32x4 acc[MT][NT];
    #pragma unroll
    for (int i = 0; i < MT; ++i)
        #pragma unroll
        for (int j = 0; j < NT; ++j)
            acc[i][j] = (f32x4){0.f, 0.f, 0.f, 0.f};

    for (int k0 = 0; k0 < K; k0 += 32) {
        #pragma unroll
        for (int i = 0; i < BN / 64; ++i) {
            const int row = (w * (BN / 64) + i) * 16 + lrow;
            const int c = lslot ^ ((row >> 2) & 3);
            gl2lds16(B + (size_t)(bn + row) * LDB + k0 + c * 8,
                     &Bs[row * 32 + lslot * 8]);
        }
        #pragma unroll
        for (int i = 0; i < BM / 64; ++i) {
            const int row = (w * (BM / 64) + i) * 16 + lrow;
            const int c = lslot ^ ((row >> 2) & 3);
            gl2lds16(A + (size_t)(bm + row) * LDA + k0 + c * 8,
                     &As[row * 32 + lslot * 8]);
        }
        __syncthreads();

        short8 af[MT], bfr[NT];
        #pragma unroll
        for (int i = 0; i < MT; ++i) {
            const int row = wr + i * 16 + m16;
            const int s = quad ^ ((row >> 2) & 3);
            af[i] = *reinterpret_cast<const short8*>(&As[row * 32 + s * 8]);
        }
        #pragma unroll
        for (int j = 0; j < NT; ++j) {
            const int row = wc + j * 16 + m16;
            const int s = quad ^ ((row >> 2) & 3);
            bfr[j] = *reinterpret_cast<const short8*>(&Bs[row * 32 + s * 8]);
        }
        #pragma unroll
        for (int i = 0; i < MT; ++i)
            #pragma unroll
            for (int j = 0; j < NT; ++j)
                acc[i][j] = __builtin_amdgcn_mfma_f32_16x16x32_bf16(
                    af[i], bfr[j], acc[i][j], 0, 0, 0);
        __syncthreads();
    }

    #pragma unroll
    for (int j = 0; j < NT; ++j) {
        const int col = bn + wc + j * 16 + m16;
        #pragma unroll
        for (int i = 0; i < MT; ++i)
            #pragma unroll
            for (int r = 0; r < 4; ++r) {
                const int row = bm + wr + i * 16 + quad * 4 + r;
                C[(size_t)row * LDC + col] = acc[i][j][r];
            }
    }
}

// ---------------- fused MLP v2 ----------------
// One block = 64 rows. LDS: As = poly(q) [64][256] bf16 (full K, staged once),
// Hs = H half [64][256] bf16. Swizzled layouts (slot = chunk ^ (row&7)) as in R3.
// W1^T/W2^T fragments are register-pipelined from global (2-slot prefetch with
// prologues issued behind independent compute) -> no staging barriers in k-loops.

__global__ __launch_bounds__(256, 2)
void fused_mlp(const float* __restrict__ q,      // [ROWS][64] fp32 (aliases out)
               const u16* __restrict__ W1t,      // [512][256] bf16
               const float* __restrict__ b1,     // [512]
               const u16* __restrict__ W2t,      // [64][512] bf16
               const float* __restrict__ b2,     // [256] (first 64 used)
               const float* __restrict__ coeffs, // [4]
               float* __restrict__ out)          // [ROWS][64] fp32
{
    __shared__ u16 As[64 * 256];
    __shared__ u16 Hs[64 * 256];

    const int tid = threadIdx.x;
    const int w = tid >> 6, lane = tid & 63;
    const int m16 = lane & 15, quad = lane >> 4;
    const long bm = (long)blockIdx.x * 64;

    short8 bf[2][4], wf[2][4];

    auto ld_bf = [&](int h, int ks, int slot) {
        #pragma unroll
        for (int j = 0; j < 4; ++j)
            bf[slot][j] = *reinterpret_cast<const short8*>(
                &W1t[(size_t)(h * 256 + w * 64 + j * 16 + m16) * 256 + ks * 32 + quad * 8]);
    };
    auto ld_wf = [&](int h, int ks, int slot) {
        #pragma unroll
        for (int j = 0; j < 4; ++j)
            wf[slot][j] = *reinterpret_cast<const short8*>(
                &W2t[(size_t)(j * 16 + m16) * 512 + h * 256 + ks * 32 + quad * 8]);
    };

    // prologue for stage1 h=0 — in flight behind all of phase 0
    ld_bf(0, 0, 0);
    ld_bf(0, 1, 1);

    const float c0 = coeffs[0], c1 = coeffs[1], c2 = coeffs[2], c3 = coeffs[3];

    // ---- phase 0: poly-expand q -> As (64 rows x 256 k, swizzled bf16) ----
    {
        const int r = tid >> 2;      // row 0..63
        const int ci = tid & 3;
        const float* qrow = q + (bm + r) * 64;
        #pragma unroll
        for (int s = 0; s < 8; ++s) {
            const int c = ci + 4 * s;          // logical chunk, k = c*8
            const int k0c = c * 8;
            const int oct = k0c >> 6;
            const int d0 = k0c & 63;
            const float4 v0 = *reinterpret_cast<const float4*>(qrow + d0);
            const float4 v1 = *reinterpret_cast<const float4*>(qrow + d0 + 4);
            const float xs[8] = {v0.x, v0.y, v0.z, v0.w, v1.x, v1.y, v1.z, v1.w};
            const float coef = (oct == 0) ? c0 : (oct == 1) ? c1 : (oct == 2) ? c2 : c3;
            short8 sv;
            #pragma unroll
            for (int j = 0; j < 8; ++j) {
                float p;
                if (oct == 0) {
                    p = c0;
                } else {
                    const float x = fminf(fmaxf(xs[j], -10.f), 10.f);
                    float t = x;
                    if (oct >= 2) t *= x;
                    if (oct == 3) t *= x;
                    p = fminf(fmaxf(coef * t, -1e6f), 1e6f);
                }
                sv[j] = (short)f2bf(p);
            }
            const int slot = c ^ (r & 7);
            *reinterpret_cast<short8*>(&As[r * 256 + slot * 8]) = sv;
        }
    }

    f32x4 acc1[4][4];
    f32x4 acc2[4];
    #pragma unroll
    for (int j = 0; j < 4; ++j) acc2[j] = (f32x4){0.f, 0.f, 0.f, 0.f};

    auto stage1 = [&](int h) {
        #pragma unroll
        for (int i = 0; i < 4; ++i)
            #pragma unroll
            for (int j = 0; j < 4; ++j)
                acc1[i][j] = (f32x4){0.f, 0.f, 0.f, 0.f};
        #pragma unroll
        for (int ks = 0; ks < 8; ++ks) {
            short8 af[4];
            #pragma unroll
            for (int i = 0; i < 4; ++i) {
                const int row = i * 16 + m16;
                const int slot = (ks * 4 + quad) ^ (row & 7);
                af[i] = *reinterpret_cast<const short8*>(&As[row * 256 + slot * 8]);
            }
            #pragma unroll
            for (int i = 0; i < 4; ++i)
                #pragma unroll
                for (int j = 0; j < 4; ++j)
                    acc1[i][j] = __builtin_amdgcn_mfma_f32_16x16x32_bf16(
                        af[i], bf[ks & 1][j], acc1[i][j], 0, 0, 0);
            if (ks < 6) ld_bf(h, ks + 2, ks & 1);
        }
    };

    auto storeH = [&](int h) {
        #pragma unroll
        for (int j = 0; j < 4; ++j) {
            const int nl = w * 64 + j * 16 + m16;      // local col 0..255
            const float bv = b1[h * 256 + nl];
            #pragma unroll
            for (int i = 0; i < 4; ++i) {
                #pragma unroll
                for (int r = 0; r < 4; ++r) {
                    const int row = i * 16 + quad * 4 + r;
                    const int slot = (nl >> 3) ^ (row & 7);
                    const float v = fmaxf(acc1[i][j][r] + bv, 0.f);
                    Hs[row * 256 + slot * 8 + (nl & 7)] = f2bf(v);
                }
            }
        }
    };

    auto stage2 = [&](int h) {
        #pragma unroll
        for (int ks = 0; ks < 8; ++ks) {
            const int row = w * 16 + m16;
            const int slot = (ks * 4 + quad) ^ (row & 7);
            const short8 hf = *reinterpret_cast<const short8*>(&Hs[row * 256 + slot * 8]);
            #pragma unroll
            for (int j = 0; j < 4; ++j)
                acc2[j] = __builtin_amdgcn_mfma_f32_16x16x32_bf16(
                    hf, wf[ks & 1][j], acc2[j], 0, 0, 0);
            if (ks < 6) ld_wf(h, ks + 2, ks & 1);
        }
    };

    __syncthreads();            // As ready
    stage1(0);
    storeH(0);
    ld_wf(0, 0, 0);             // stage2(0) prologue — hidden behind stage1(1)
    ld_wf(0, 1, 1);
    ld_bf(1, 0, 0);             // stage1(1) prologue
    ld_bf(1, 1, 1);
    __syncthreads();            // Hs(0) visible to all waves
    stage1(1);
    stage2(0);
    __syncthreads();            // all waves done reading Hs(0)
    storeH(1);
    ld_wf(1, 0, 0);             // stage2(1) prologue
    ld_wf(1, 1, 1);
    __syncthreads();            // Hs(1) visible
    stage2(1);

    // ---- epilogue: out rows bm + w*16 + quad*4 + r ----
    #pragma unroll
    for (int j = 0; j < 4; ++j) {
        const int col = j * 16 + m16;
        const float bv = b2[col];
        #pragma unroll
        for (int r = 0; r < 4; ++r) {
            const long row = bm + w * 16 + quad * 4 + r;
            out[row * 64 + col] = acc2[j][r] + bv;
        }
    }
}

// ---------------- host ----------------

extern "C" void kernel_launch(void* const* d_in, const int* in_sizes, int n_in,
                              void* d_out, int out_size, void* d_ws, size_t ws_size,
                              hipStream_t stream) {
    const float* X      = (const float*)d_in[0];
    const float* Wq     = (const float*)d_in[1];
    const float* coeffs = (const float*)d_in[2];
    const float* W1     = (const float*)d_in[3];
    const float* b1     = (const float*)d_in[4];
    const float* W2     = (const float*)d_in[5];
    const float* b2     = (const float*)d_in[6];
    float* out = (float*)d_out;            // q staging (fp32) then final out

    char* ws = (char*)d_ws;
    u16* Xb  = (u16*)(ws);
    u16* Wqb = (u16*)(ws + 12582912);
    u16* W1b = (u16*)(ws + 13762560);
    u16* W2b = (u16*)(ws + 14024704);

    cast_f32_bf16<<<6144, 256, 0, stream>>>(X, Xb, 8192 * 768 / 4);
    transpose_cast<<<dim3(24, 24), dim3(32, 8), 0, stream>>>(Wq, Wqb, 768, 768);
    transpose_cast<<<dim3(16, 8),  dim3(32, 8), 0, stream>>>(W1, W1b, 256, 512);
    transpose_cast<<<dim3(2, 16),  dim3(32, 8), 0, stream>>>(W2, W2b, 512, 256);

    // GEMM1: q = Xb @ Wqb^T -> fp32 in d_out. M=8192 N=768 K=768.
    // 64x128 tile -> 768 blocks (3/CU resident) instead of 384.
    mfma_gemm<64, 128, 32, 64, 768, 768, 768, 768>
        <<<dim3(128, 6), 256, 0, stream>>>(Xb, Wqb, out);

    // Fused MLP over all 98304 rows; 64 rows/block.
    fused_mlp<<<1536, 256, 0, stream>>>(out, W1b, b1, W2b, b2, coeffs, out);
}

// Round 5
// 200.452 us; speedup vs baseline: 1.0868x; 1.0553x over previous
//
#include <hip/hip_runtime.h>

// AtlasAttention bf16-MFMA v3 — occupancy-first 3-GEMM pipeline.
// out = MLP2(relu(MLP1(poly(clip(X@Wq)))))[:, :64], heads folded.
// All GEMMs: 64x64 block tile, 4 waves of 32x32 wave tiles, 8 KB LDS,
// low VGPR -> 5+ blocks/CU resident (theory: util scales with resident waves).
// q is bf16 in ws ([98304][64] flat == [8192][768] flat). H chunked L3-resident.
//
// ws layout (bytes):
//   Xb   @ 0          : 8192*768 bf16   = 12,582,912
//   Wqb  @ 12,582,912 : 768*768  bf16^T = 1,179,648   (Wqb[n][k])
//   W1b  @ 13,762,560 : 512*256  bf16^T = 262,144     (W1b[n][k])
//   W2b  @ 14,024,704 : 64*512   bf16^T = 65,536      (W2b[n][k], first 64 cols)
//   Qb   @ 14,090,240 : 98304*64 bf16   = 12,582,912
//   Hb   @ 26,673,152 : chunk*512 bf16  (<= 50,331,648 for 49152-row chunks)

typedef unsigned short u16;
typedef __attribute__((ext_vector_type(8))) short short8;
typedef __attribute__((ext_vector_type(8))) u16 u16x8;
typedef __attribute__((ext_vector_type(4))) float f32x4;
typedef __attribute__((ext_vector_type(4))) u16 u16x4;

__device__ __forceinline__ u16 f2bf(float f) {
    unsigned u = __builtin_bit_cast(unsigned, f);
    u += 0x7FFFu + ((u >> 16) & 1u);   // RNE
    return (u16)(u >> 16);
}
__device__ __forceinline__ float bf2f(u16 h) {
    return __builtin_bit_cast(float, (unsigned)h << 16);
}

__device__ __forceinline__ void gl2lds16(const void* g, void* l) {
    __builtin_amdgcn_global_load_lds(
        (const __attribute__((address_space(1))) unsigned int*)g,
        (__attribute__((address_space(3))) unsigned int*)l, 16, 0, 0);
}

// ---------------- conversion kernels ----------------

__global__ __launch_bounds__(256) void cast_f32_bf16(const float* __restrict__ in,
                                                     u16* __restrict__ out, int n4) {
    int i = blockIdx.x * 256 + threadIdx.x;
    if (i < n4) {
        float4 v = reinterpret_cast<const float4*>(in)[i];
        u16x4 o = {f2bf(v.x), f2bf(v.y), f2bf(v.z), f2bf(v.w)};
        reinterpret_cast<u16x4*>(out)[i] = o;
    }
}

// in: [R][Cin] fp32; out: [C][R] bf16 (first C cols). grid (C/32, R/32), block (32,8).
__global__ __launch_bounds__(256) void transpose_cast(const float* __restrict__ in,
                                                      u16* __restrict__ out,
                                                      int R, int Cin) {
    __shared__ float t[32][33];
    const int c0 = blockIdx.x * 32, r0 = blockIdx.y * 32;
    const int tx = threadIdx.x, ty = threadIdx.y;
    #pragma unroll
    for (int j = 0; j < 32; j += 8)
        t[ty + j][tx] = in[(size_t)(r0 + ty + j) * Cin + c0 + tx];
    __syncthreads();
    #pragma unroll
    for (int j = 0; j < 32; j += 8)
        out[(size_t)(c0 + ty + j) * R + r0 + tx] = f2bf(t[tx][ty + j]);
}

// ---------------- 64x64 MFMA GEMM (occupancy-tuned) ----------------
// C[M][N] = A[M][K] @ B^T[N][K]. 4 waves, wave tile 32x32 (MT=NT=2).
// LDS: As/Bs 64 rows x 32 k bf16, swizzled: chunk c at slot c^((row>>2)&3).
// POLY: A is q bf16 [M][64]; A-tile is poly-expanded during staging (ds_write path).

template<int BM, int BN, int K, int LDA, int LDB, int LDC,
         bool POLY, bool RELU, bool BIAS, bool OUTBF>
__global__ __launch_bounds__(256, 5)
void mfma_gemm(const u16* __restrict__ A, const u16* __restrict__ B,
               const float* __restrict__ bias, const float* __restrict__ coeffs,
               void* __restrict__ Cv)
{
    __shared__ u16 As[BM * 32];
    __shared__ u16 Bs[BN * 32];

    const int tid = threadIdx.x;
    const int w = tid >> 6, lane = tid & 63;
    const int lrow = lane >> 2, lslot = lane & 3;
    const int m16 = lane & 15, quad = lane >> 4;
    const int bm = blockIdx.x * BM, bn = blockIdx.y * BN;
    const int wr = (w & 1) * 32, wc = (w >> 1) * 32;

    float c0 = 0.f, c1 = 0.f, c2 = 0.f, c3 = 0.f;
    if constexpr (POLY) { c0 = coeffs[0]; c1 = coeffs[1]; c2 = coeffs[2]; c3 = coeffs[3]; }

    f32x4 acc[2][2];
    #pragma unroll
    for (int i = 0; i < 2; ++i)
        #pragma unroll
        for (int j = 0; j < 2; ++j)
            acc[i][j] = (f32x4){0.f, 0.f, 0.f, 0.f};

    for (int k0 = 0; k0 < K; k0 += 32) {
        const int row = w * 16 + lrow;                 // 0..63 across 4 waves
        const int c = lslot ^ ((row >> 2) & 3);        // swizzled k-chunk
        // ---- stage B ----
        gl2lds16(B + (size_t)(bn + row) * LDB + k0 + c * 8,
                 &Bs[row * 32 + lslot * 8]);
        // ---- stage A ----
        if constexpr (POLY) {
            const int oct = k0 >> 6;                   // wave-uniform
            const int d0 = (k0 & 63) + c * 8;
            const u16x8 qv = *reinterpret_cast<const u16x8*>(
                A + (size_t)(bm + row) * LDA + d0);
            const float coef = (oct == 0) ? c0 : (oct == 1) ? c1 : (oct == 2) ? c2 : c3;
            short8 sv;
            #pragma unroll
            for (int j = 0; j < 8; ++j) {
                float p;
                if (oct == 0) {
                    p = c0;
                } else {
                    const float x = fminf(fmaxf(bf2f(qv[j]), -10.f), 10.f);
                    float t = x;
                    if (oct >= 2) t *= x;
                    if (oct == 3) t *= x;
                    p = fminf(fmaxf(coef * t, -1e6f), 1e6f);
                }
                sv[j] = (short)f2bf(p);
            }
            *reinterpret_cast<short8*>(&As[row * 32 + lslot * 8]) = sv;
        } else {
            gl2lds16(A + (size_t)(bm + row) * LDA + k0 + c * 8,
                     &As[row * 32 + lslot * 8]);
        }
        __syncthreads();

        short8 af[2], bfr[2];
        #pragma unroll
        for (int i = 0; i < 2; ++i) {
            const int r = wr + i * 16 + m16;
            const int s = quad ^ ((r >> 2) & 3);
            af[i] = *reinterpret_cast<const short8*>(&As[r * 32 + s * 8]);
        }
        #pragma unroll
        for (int j = 0; j < 2; ++j) {
            const int r = wc + j * 16 + m16;
            const int s = quad ^ ((r >> 2) & 3);
            bfr[j] = *reinterpret_cast<const short8*>(&Bs[r * 32 + s * 8]);
        }
        #pragma unroll
        for (int i = 0; i < 2; ++i)
            #pragma unroll
            for (int j = 0; j < 2; ++j)
                acc[i][j] = __builtin_amdgcn_mfma_f32_16x16x32_bf16(
                    af[i], bfr[j], acc[i][j], 0, 0, 0);
        __syncthreads();
    }

    // ---- epilogue: C[row = quad*4+reg][col = lane&15] per 16x16 tile ----
    #pragma unroll
    for (int j = 0; j < 2; ++j) {
        const int col = bn + wc + j * 16 + m16;
        float bv = 0.f;
        if constexpr (BIAS) bv = bias[col];
        #pragma unroll
        for (int i = 0; i < 2; ++i) {
            #pragma unroll
            for (int r = 0; r < 4; ++r) {
                const int row = bm + wr + i * 16 + quad * 4 + r;
                float v = acc[i][j][r] + bv;
                if constexpr (RELU) v = fmaxf(v, 0.f);
                if constexpr (OUTBF)
                    ((u16*)Cv)[(size_t)row * LDC + col] = f2bf(v);
                else
                    ((float*)Cv)[(size_t)row * LDC + col] = v;
            }
        }
    }
}

// ---------------- host ----------------

extern "C" void kernel_launch(void* const* d_in, const int* in_sizes, int n_in,
                              void* d_out, int out_size, void* d_ws, size_t ws_size,
                              hipStream_t stream) {
    const float* X      = (const float*)d_in[0];
    const float* Wq     = (const float*)d_in[1];
    const float* coeffs = (const float*)d_in[2];
    const float* W1     = (const float*)d_in[3];
    const float* b1     = (const float*)d_in[4];
    const float* W2     = (const float*)d_in[5];
    const float* b2     = (const float*)d_in[6];
    float* out = (float*)d_out;

    char* ws = (char*)d_ws;
    u16* Xb  = (u16*)(ws);
    u16* Wqb = (u16*)(ws + 12582912);
    u16* W1b = (u16*)(ws + 13762560);
    u16* W2b = (u16*)(ws + 14024704);
    u16* Qb  = (u16*)(ws + 14090240);
    u16* Hb  = (u16*)(ws + 26673152);
    const size_t reserved = 26673152;

    cast_f32_bf16<<<6144, 256, 0, stream>>>(X, Xb, 8192 * 768 / 4);
    transpose_cast<<<dim3(24, 24), dim3(32, 8), 0, stream>>>(Wq, Wqb, 768, 768);
    transpose_cast<<<dim3(16, 8),  dim3(32, 8), 0, stream>>>(W1, W1b, 256, 512);
    transpose_cast<<<dim3(2, 16),  dim3(32, 8), 0, stream>>>(W2, W2b, 512, 256);

    // GEMM1: Qb = bf16(Xb @ Wqb^T). M=8192 N=768 K=768. grid 128x12 = 1536 blocks.
    mfma_gemm<64, 64, 768, 768, 768, 768, false, false, false, true>
        <<<dim3(128, 12), 256, 0, stream>>>(Xb, Wqb, nullptr, nullptr, Qb);

    const long ROWS = 98304;
    long ch = (long)((ws_size > reserved ? ws_size - reserved : 0) / 1024); // 512 bf16/row
    ch &= ~63L;
    if (ch > 49152) ch = 49152;   // 50 MB H chunk stays L3-resident
    if (ch < 64) ch = 64;

    for (long r0 = 0; r0 < ROWS; r0 += ch) {
        const long rows = (ROWS - r0 < ch) ? (ROWS - r0) : ch;
        // GEMM2: Hb = bf16(relu(poly(Qb) @ W1b^T + b1)). M=rows N=512 K=256.
        mfma_gemm<64, 64, 256, 64, 256, 512, true, true, true, true>
            <<<dim3(rows / 64, 8), 256, 0, stream>>>(
                Qb + r0 * 64, W1b, b1, coeffs, Hb);
        // GEMM3: out = Hb @ W2b^T + b2 (fp32). M=rows N=64 K=512.
        mfma_gemm<64, 64, 512, 512, 512, 64, false, false, true, false>
            <<<dim3(rows / 64, 1), 256, 0, stream>>>(
                Hb, W2b, b2, nullptr, out + r0 * 64);
    }
}